// Round 5
// baseline (1343.941 us; speedup 1.0000x reference)
//
#include <hip/hip_runtime.h>
#include <hip/hip_bf16.h>

typedef __attribute__((ext_vector_type(8))) short bfrag_t;   // 8 bf16 (4 VGPRs)
typedef __attribute__((ext_vector_type(4))) float accum_t;   // 4 f32

static_assert(sizeof(bfrag_t) == 16, "frag size");

static constexpr int M_NODES = 50000;
static constexpr int E_EDGES = 156000;
static constexpr int D       = 512;
static constexpr int MT256   = (M_NODES + 255) / 256;  // 196 M-tiles
static constexpr int NT128   = 4;                      // 512/128 N-tiles
static constexpr int NWG     = MT256 * NT128;          // 784 (784 % 8 == 0)
static constexpr int XQ      = NWG / 8;                // 98

// ---- manual RNE f32 -> bf16 ----
__device__ __forceinline__ unsigned short f2bf(float f) {
  unsigned int u = __float_as_uint(f);
  u = (u + 0x7FFFu + ((u >> 16) & 1u)) >> 16;
  return (unsigned short)u;
}

__device__ __forceinline__ void gll16(const unsigned short* g, unsigned short* l) {
  __builtin_amdgcn_global_load_lds(
      (const __attribute__((address_space(1))) void*)g,
      (__attribute__((address_space(3))) void*)l,
      16, 0, 0);
}

// ---------------- weight cast + transpose: Wt[mat][n][k] = bf16(W[mat][k][n]) ----
__global__ void cast_w_kernel(const float* __restrict__ Wself,
                              const float* __restrict__ W1,
                              const float* __restrict__ W2,
                              unsigned short* __restrict__ Wt) {
  int idx = blockIdx.x * 256 + threadIdx.x;
  if (idx >= 7 * 262144) return;
  int mat = idx >> 18;
  int rem = idx & 262143;
  int k = rem >> 9;
  int n = rem & 511;
  float v;
  if (mat == 0)      v = Wself[rem];
  else if (mat <= 3) v = W1[(size_t)(mat - 1) * 262144 + rem];
  else               v = W2[(size_t)(mat - 4) * 262144 + rem];
  Wt[(size_t)mat * 262144 + (size_t)n * 512 + k] = f2bf(v);
}

// ---------------- h = bf16(x [+ agg]) ----------------
template <bool USE_AGG>
__global__ void build_h_kernel(const float* __restrict__ x,
                               const float* __restrict__ agg,
                               unsigned short* __restrict__ h, int n) {
  int stride = gridDim.x * blockDim.x;
  int n4 = n >> 2;
  for (int i = blockIdx.x * blockDim.x + threadIdx.x; i < n4; i += stride) {
    float4 v = ((const float4*)x)[i];
    if (USE_AGG) {
      float4 a = ((const float4*)agg)[i];
      v.x += a.x; v.y += a.y; v.z += a.z; v.w += a.w;
    }
    ushort4 u;
    u.x = f2bf(v.x); u.y = f2bf(v.y); u.z = f2bf(v.z); u.w = f2bf(v.w);
    ((ushort4*)h)[i] = u;
  }
}

// ---------------- scatter: agg[dst] += x[src] for edges of type rel ----------
__global__ void scatter_kernel(const float* __restrict__ x,
                               const int* __restrict__ ei,
                               const int* __restrict__ et,
                               int rel, float* __restrict__ agg) {
  int e    = blockIdx.x * 4 + (threadIdx.x >> 6);
  int lane = threadIdx.x & 63;
  if (e >= E_EDGES) return;
  if (et[e] != rel) return;
  int src = ei[e];
  int dst = ei[E_EDGES + e];
  const float* xs = x + (size_t)src * D;
  float* ad = agg + (size_t)dst * D;
  float v[8];
#pragma unroll
  for (int j = 0; j < 8; ++j) v[j] = xs[j * 64 + lane];
#pragma unroll
  for (int j = 0; j < 8; ++j) unsafeAtomicAdd(ad + j * 64 + lane, v[j]);
}

// ---------------- GEMM: C[M,512] = A[M,512](bf16) @ B[512,512] + bias --------
// 8-wave 256x128 tile, BK=64, 3-slot LDS ring, 2-phase/K-tile interleave,
// counted vmcnt(6) (T3/T4), setprio (T5), XCD swizzle (T1).
// MODE 0: f32 store. 1: relu->bf16. 2: f32 RMW accumulate.
template <int MODE>
__global__ __launch_bounds__(512) void gemm_kernel(
    const unsigned short* __restrict__ A,
    const unsigned short* __restrict__ Bt,
    const float* __restrict__ bias,
    float* __restrict__ outF,
    unsigned short* __restrict__ outB) {
  // slot layout (ushorts): A [kc(8)][row(256)][8] at 0..16383,
  //                        B [kc(8)][col(128)][8] at 16384..24575
  __shared__ alignas(16) unsigned short L[3][24576];  // 144 KB
  const int tid  = threadIdx.x;
  const int lane = tid & 63;
  const int wid  = tid >> 6;
  const int wr   = wid >> 1;   // 0..3 : 64-row band within 256
  const int wc   = wid & 1;    // 0..1 : 64-col band within 128

  // T1: XCD-chunked swizzle (NWG % 8 == 0 -> simple form is bijective)
  const int orig = blockIdx.x;
  const int swz  = (orig & 7) * XQ + (orig >> 3);
  const int tileM = (swz >> 2) * 256;
  const int tileN = (swz & 3) * 128;

  accum_t acc[4][4] = {};

  // --- staging maps (gll16: wave-uniform base + lane*16B, LDS linear) ---
  // A: 4 loads/thread. load j: kc = j*2 + (tid>>8), row = tid&255
  const int rowA = tid & 255;
  int garow = tileM + rowA; garow = garow < M_NODES ? garow : M_NODES - 1;
  const unsigned short* gA = A + (size_t)garow * D + (tid >> 8) * 8;  // +kt*64 + j*16
  const int ldsA = (tid >> 8) * 2048 + rowA * 8;                      // +j*4096
  // B: 2 loads/thread. load j: kc = j*4 + (tid>>7), col = tid&127
  const int colB = tid & 127;
  const unsigned short* gB = Bt + (size_t)(tileN + colB) * D + (tid >> 7) * 8;  // +kt*64 + j*32
  const int ldsB = 16384 + (tid >> 7) * 1024 + colB * 8;                        // +j*4096

#define STAGE_H1(slot, kt)                                   \
  do {                                                       \
    gll16(gA + (kt) * 64 + 0 * 16, &L[(slot)][ldsA + 0 * 4096]); \
    gll16(gA + (kt) * 64 + 1 * 16, &L[(slot)][ldsA + 1 * 4096]); \
    gll16(gB + (kt) * 64 + 0 * 32, &L[(slot)][ldsB + 0 * 4096]); \
  } while (0)
#define STAGE_H2(slot, kt)                                   \
  do {                                                       \
    gll16(gA + (kt) * 64 + 2 * 16, &L[(slot)][ldsA + 2 * 4096]); \
    gll16(gA + (kt) * 64 + 3 * 16, &L[(slot)][ldsA + 3 * 4096]); \
    gll16(gB + (kt) * 64 + 1 * 32, &L[(slot)][ldsB + 1 * 4096]); \
  } while (0)

  // --- fragment read offsets (ushorts within slot) ---
  const int kcl = lane >> 4;       // k-chunk within 32-k sub-tile
  const int fr  = lane & 15;
  const int aoff = kcl * 2048 + (wr * 64 + fr) * 8;           // + s*8192 + m*128
  const int boff = 16384 + kcl * 1024 + (wc * 64 + fr) * 8;   // + s*4096 + n*128

  // prologue: K-tiles 0 and 1 fully staged (12 loads in flight)
  STAGE_H1(0, 0); STAGE_H2(0, 0);
  STAGE_H1(1, 1); STAGE_H2(1, 1);

#pragma unroll
  for (int kt = 0; kt < 8; ++kt) {
    const int slot = kt % 3;
    if (kt == 7) { asm volatile("s_waitcnt vmcnt(0)" ::: "memory"); }
    else         { asm volatile("s_waitcnt vmcnt(6)" ::: "memory"); }  // kt landed; kt+1 in flight
    __builtin_amdgcn_s_barrier();   // buf[slot] ready for all waves

    const unsigned short* Ls = &L[slot][0];
    // ---- phase 0: B (8) + A m0,m1 (4) reads, stage half of kt+2, 16 MFMA ----
    bfrag_t b[2][4], a0[2][2];
#pragma unroll
    for (int s = 0; s < 2; ++s)
#pragma unroll
      for (int n = 0; n < 4; ++n)
        b[s][n] = *(const bfrag_t*)(Ls + boff + s * 4096 + n * 128);
#pragma unroll
    for (int s = 0; s < 2; ++s)
#pragma unroll
      for (int mm = 0; mm < 2; ++mm)
        a0[s][mm] = *(const bfrag_t*)(Ls + aoff + s * 8192 + mm * 128);
    if (kt < 6) STAGE_H1((kt + 2) % 3, kt + 2);
    __builtin_amdgcn_s_setprio(1);
#pragma unroll
    for (int mm = 0; mm < 2; ++mm)
#pragma unroll
      for (int n = 0; n < 4; ++n)
#pragma unroll
        for (int s = 0; s < 2; ++s)
          acc[mm][n] = __builtin_amdgcn_mfma_f32_16x16x32_bf16(a0[s][mm], b[s][n], acc[mm][n], 0, 0, 0);
    __builtin_amdgcn_s_setprio(0);
    __builtin_amdgcn_s_barrier();

    // ---- phase 1: A m2,m3 (4) reads, stage rest of kt+2, 16 MFMA ----
    bfrag_t a1[2][2];
#pragma unroll
    for (int s = 0; s < 2; ++s)
#pragma unroll
      for (int mm = 0; mm < 2; ++mm)
        a1[s][mm] = *(const bfrag_t*)(Ls + aoff + s * 8192 + (2 + mm) * 128);
    if (kt < 6) STAGE_H2((kt + 2) % 3, kt + 2);
    __builtin_amdgcn_s_setprio(1);
#pragma unroll
    for (int mm = 0; mm < 2; ++mm)
#pragma unroll
      for (int n = 0; n < 4; ++n)
#pragma unroll
        for (int s = 0; s < 2; ++s)
          acc[2 + mm][n] = __builtin_amdgcn_mfma_f32_16x16x32_bf16(a1[s][mm], b[s][n], acc[2 + mm][n], 0, 0, 0);
    __builtin_amdgcn_s_setprio(0);
    // next kt's vmcnt+barrier is the trailing boundary
  }
#undef STAGE_H1
#undef STAGE_H2

  // epilogue: C row = (lane>>4)*4 + q, col = lane&15 within each 16x16 frag
  const int rq = lane >> 4;
#pragma unroll
  for (int n = 0; n < 4; ++n) {
    const int col = tileN + wc * 64 + n * 16 + fr;
    const float bv = bias[col];
#pragma unroll
    for (int m = 0; m < 4; ++m) {
      const int rbase = tileM + wr * 64 + m * 16 + rq * 4;
#pragma unroll
      for (int q = 0; q < 4; ++q) {
        const int row = rbase + q;
        if (row < M_NODES) {
          float v = acc[m][n][q] + bv;
          const size_t idx = (size_t)row * D + col;
          if (MODE == 0)      outF[idx] = v;
          else if (MODE == 1) outB[idx] = f2bf(fmaxf(v, 0.f));
          else                outF[idx] += v;
        }
      }
    }
  }
}

extern "C" void kernel_launch(void* const* d_in, const int* in_sizes, int n_in,
                              void* d_out, int out_size, void* d_ws, size_t ws_size,
                              hipStream_t stream) {
  const float* x     = (const float*)d_in[0];
  const int*   ei    = (const int*)d_in[1];
  const int*   et    = (const int*)d_in[2];
  const float* Wself = (const float*)d_in[3];
  const float* bself = (const float*)d_in[4];
  const float* W1    = (const float*)d_in[5];
  const float* b1    = (const float*)d_in[6];
  const float* W2    = (const float*)d_in[7];
  const float* b2    = (const float*)d_in[8];
  float* out = (float*)d_out;

  char* ws = (char*)d_ws;
  unsigned short* h   = (unsigned short*)ws;               // 51.2 MB  bf16 A operand
  float*          agg = (float*)(ws + 51200000);           // 102.4 MB fp32 segment-sum
  unsigned short* mid = (unsigned short*)(ws + 51200000);  // aliases agg (51.2 MB bf16)
  unsigned short* Wt  = (unsigned short*)(ws + 153600000); // 3.67 MB  bf16 W^T x7

  cast_w_kernel<<<7 * 1024, 256, 0, stream>>>(Wself, W1, W2, Wt);
  build_h_kernel<false><<<2048, 256, 0, stream>>>(x, nullptr, h, M_NODES * D);
  gemm_kernel<0><<<NWG, 512, 0, stream>>>(h, Wt, bself, out, nullptr);

  for (int r = 0; r < 3; ++r) {
    hipMemsetAsync(agg, 0, (size_t)M_NODES * D * sizeof(float), stream);
    scatter_kernel<<<(E_EDGES + 3) / 4, 256, 0, stream>>>(x, ei, et, r, agg);
    build_h_kernel<true><<<2048, 256, 0, stream>>>(x, agg, h, M_NODES * D);
    gemm_kernel<1><<<NWG, 512, 0, stream>>>(h, Wt + (size_t)(1 + r) * 262144,
                                            b1 + (size_t)r * 512, nullptr, mid);
    gemm_kernel<2><<<NWG, 512, 0, stream>>>(mid, Wt + (size_t)(4 + r) * 262144,
                                            b2 + (size_t)r * 512, out, nullptr);
  }
}